// Round 10
// baseline (145.672 us; speedup 1.0000x reference)
//
#include <hip/hip_runtime.h>
#include <hip/hip_bf16.h>

// Shapes (fixed by the problem)
#define NB   16    // batch
#define NC   512   // channels
#define NSPA 1024  // h*w
#define GN_EPS 1e-5f
#define SCL 0.044194173824159216f  // 512^-0.5

typedef __bf16 bf16x8 __attribute__((ext_vector_type(8)));
typedef __bf16 bf16x4 __attribute__((ext_vector_type(4)));
typedef float  f32x4  __attribute__((ext_vector_type(4)));

typedef __attribute__((address_space(3))) void lds_t;
typedef const __attribute__((address_space(1))) void gl_t;
#define GLDS16(g, l) __builtin_amdgcn_global_load_lds((gl_t*)(g), (lds_t*)(l), 16, 0, 0)

__device__ __forceinline__ __bf16 tob(float f) { return (__bf16)f; }

// Bijective XCD-chunk swizzle (T1): each XCD gets a contiguous logical chunk.
__device__ __forceinline__ int xcd_swz(int cpx) {
  return (blockIdx.x & 7) * cpx + (blockIdx.x >> 3);
}

// ===========================================================================
// K1: prep — one launch, heterogeneous blocks (grid 784):
//   id <  512 : fused GroupNorm(stats+apply) + transpose -> xnT[b][n][c] bf16
//   id <  704 : 64x64 transpose tiles wqT/wkT/wvT[c][o] bf16  (192 blocks)
//   id <  768 : pack Wout natural -> wob bf16                  (64 blocks)
//   id <  776 : rvec[c] = sum_o Wk[o][c]*bq[o]                 (8 blocks)
//   id <  784 : bc[o]   = sum_c Wout[o][c]*bv[c]               (8 blocks)
// ===========================================================================
__global__ void prep_kernel(const float* __restrict__ x,
                            const float* __restrict__ gn_scale,
                            const float* __restrict__ gn_bias,
                            const float* __restrict__ wq,   // w_qkv [1536][512]
                            const float* __restrict__ wo,   // w_out [512][512]
                            const float* __restrict__ bqkv, // [1536]
                            __bf16* __restrict__ xnT, __bf16* __restrict__ wqT,
                            __bf16* __restrict__ wkT, __bf16* __restrict__ wvT,
                            __bf16* __restrict__ wob, float* __restrict__ rvec,
                            float* __restrict__ bc) {
  __shared__ __align__(16) unsigned char smem[37120];
  const int id = blockIdx.x;
  const int t = threadIdx.x;
  if (id < 512) {
    const int L = (id & 7) * 64 + (id >> 3);   // XCD-chunk swizzle (CPX=64)
    const int b = L >> 5, g = L & 31;
    const int row = t >> 4, sub = t & 15;
    const float4* bx = (const float4*)(x + (size_t)(b * NC + g * 16 + row) * NSPA);
    float4 vv[16];
    float s = 0.f, ss = 0.f;
#pragma unroll
    for (int k = 0; k < 16; ++k) {
      float4 v = bx[sub + k * 16];
      vv[k] = v;
      s  += (v.x + v.y) + (v.z + v.w);
      ss += (v.x * v.x + v.y * v.y) + (v.z * v.z + v.w * v.w);
    }
#pragma unroll
    for (int off = 32; off; off >>= 1) { s += __shfl_xor(s, off); ss += __shfl_xor(ss, off); }
    float* red = (float*)(smem + 36864);
    const int wave = t >> 6, lane = t & 63;
    if (lane == 0) { red[wave] = s; red[4 + wave] = ss; }
    __syncthreads();
    const float S  = red[0] + red[1] + red[2] + red[3];
    const float SS = red[4] + red[5] + red[6] + red[7];
    const float mean = S * (1.f / 16384.f);
    const float var  = SS * (1.f / 16384.f) - mean * mean;
    const float rstd = rsqrtf(var + GN_EPS);
    const int c = g * 16 + row;
    const float a  = gn_scale[c] * rstd;
    const float bb = gn_bias[c] - mean * a;
    __bf16 (*lt)[18] = (__bf16(*)[18])smem;   // [1024][16+2pad] bf16
#pragma unroll
    for (int k = 0; k < 16; ++k) {
      float4 v = vv[k];
      const int n0 = (sub + k * 16) * 4;
      lt[n0 + 0][row] = tob(v.x * a + bb);
      lt[n0 + 1][row] = tob(v.y * a + bb);
      lt[n0 + 2][row] = tob(v.z * a + bb);
      lt[n0 + 3][row] = tob(v.w * a + bb);
    }
    __syncthreads();
#pragma unroll
    for (int r = 0; r < 4; ++r) {
      const int n = t * 4 + r;
      const unsigned int* lr = (const unsigned int*)&lt[n][0];
      uint4 d0, d1;
      d0.x = lr[0]; d0.y = lr[1]; d0.z = lr[2]; d0.w = lr[3];
      d1.x = lr[4]; d1.y = lr[5]; d1.z = lr[6]; d1.w = lr[7];
      uint4* dst = (uint4*)(xnT + (size_t)(b * NSPA + n) * NC + g * 16);
      dst[0] = d0; dst[1] = d1;
    }
  } else if (id < 704) {
    const int id2 = id - 512;
    const int mat = id2 >> 6, tile = id2 & 63;
    const int o0 = (tile >> 3) * 64, c0 = (tile & 7) * 64;
    __bf16* dstT = (mat == 0) ? wqT : (mat == 1) ? wkT : wvT;
    __bf16 (*l)[72] = (__bf16(*)[72])smem;
    const int orr = t >> 2, seg = (t & 3) * 16;
    const float4* src = (const float4*)(wq + (size_t)(mat * NC + o0 + orr) * NC + c0 + seg);
#pragma unroll
    for (int i = 0; i < 4; ++i) {
      float4 v = src[i];
      l[seg + i * 4 + 0][orr] = tob(v.x);
      l[seg + i * 4 + 1][orr] = tob(v.y);
      l[seg + i * 4 + 2][orr] = tob(v.z);
      l[seg + i * 4 + 3][orr] = tob(v.w);
    }
    __syncthreads();
#pragma unroll
    for (int i = 0; i < 2; ++i) {
      const int chunk = t + i * 256;
      const int row = chunk >> 3, sg = chunk & 7;
      *(bf16x8*)(dstT + (size_t)(c0 + row) * NC + o0 + sg * 8) = *(const bf16x8*)&l[row][sg * 8];
    }
  } else if (id < 768) {
    const int idx = id - 704;
#pragma unroll
    for (int i = 0; i < 4; ++i) {
      const int tt = idx * 1024 + i * 256 + t;
      float4 v = ((const float4*)wo)[tt];
      bf16x4 w;
      w[0] = tob(v.x); w[1] = tob(v.y); w[2] = tob(v.z); w[3] = tob(v.w);
      *(bf16x4*)(wob + (size_t)tt * 4) = w;
    }
  } else if (id < 776) {
    const int c0 = (id - 768) * 64;
    const int lane = t & 63, wave = t >> 6;
    const int c = c0 + lane;
    float s = 0.f;
    for (int o = wave * 128; o < wave * 128 + 128; ++o)
      s += wq[(size_t)(NC + o) * NC + c] * bqkv[o];
    float* red = (float*)smem;
    red[wave * 64 + lane] = s;
    __syncthreads();
    if (wave == 0) {
      float tot = red[lane] + red[64 + lane] + red[128 + lane] + red[192 + lane];
      rvec[c] = tot;
    }
  } else {
    const int o = (id - 776) * 64 + (t >> 2);
    const int q = t & 3;
    const float4* wr = (const float4*)(wo + (size_t)o * NC + q * 128);
    const float4* bv = (const float4*)(bqkv + 2 * NC + q * 128);
    float s = 0.f;
#pragma unroll
    for (int i = 0; i < 32; ++i) {
      float4 w4 = wr[i], b4 = bv[i];
      s += (w4.x * b4.x + w4.y * b4.y) + (w4.z * b4.z + w4.w * b4.w);
    }
    s += __shfl_xor(s, 1);
    s += __shfl_xor(s, 2);
    if (q == 0) bc[o] = s;
  }
}

// ===========================================================================
// BK=32 2-phase GEMM core, 32 KB LDS -> 4 blocks/CU (the TLP that hides the
// vmcnt(0) drains; m97 mechanism). B-tile fixed 128 rows; A-tile MROWS
// (128 or 64). Row = 64 B = 4 granules of 16 B; swizzle: phys granule s of
// row r holds global granule s^((r>>1)&3) (balanced: 0-conflict class).
// Accumulation order identical to BK=64 core -> bit-identical results.
// ===========================================================================
template <int MROWS>
__device__ __forceinline__ void stage32(const __bf16* __restrict__ A, int lda,
                                        const __bf16* __restrict__ B, int ldb,
                                        int k0, __bf16* lAf, __bf16* lBf) {
  const int tid = threadIdx.x;
#pragma unroll
  for (int l = 0; l < 2; ++l) {
    const int idx = tid + l * 256;
    const int prow = idx >> 2, slot = idx & 3;
    const int sg = slot ^ ((prow >> 1) & 3);
    GLDS16(B + (size_t)prow * ldb + k0 + sg * 8, lBf + idx * 8);
  }
#pragma unroll
  for (int l = 0; l < MROWS / 64; ++l) {
    const int idx = tid + l * 256;
    const int prow = idx >> 2, slot = idx & 3;
    const int sg = slot ^ ((prow >> 1) & 3);
    GLDS16(A + (size_t)prow * lda + k0 + sg * 8, lAf + idx * 8);
  }
}

template <int MROWS>
__device__ __forceinline__ void gemm_core32(const __bf16* __restrict__ A, int lda,
                                            const __bf16* __restrict__ B, int ldb,
                                            int K, __bf16* sA, __bf16* sB,
                                            f32x4 (*acc)[4]) {
  constexpr int MH = MROWS / 32;       // m-frags per wave
  constexpr int ASLOT = MROWS * 32;
  constexpr int BSLOT = 128 * 32;
  const int tid = threadIdx.x;
  const int lane = tid & 63, wave = tid >> 6;
  const int wm = (wave >> 1) * (MROWS / 2), wn = (wave & 1) * 64;
  const int fr = lane & 15, fgh = lane >> 4;
  const int nt = K >> 5;

  stage32<MROWS>(A, lda, B, ldb, 0, sA, sB);
  asm volatile("s_waitcnt vmcnt(0)" ::: "memory");
  __syncthreads();
  int cur = 0;
  for (int t = 0; t < nt; ++t) {
    if (t + 1 < nt)
      stage32<MROWS>(A, lda, B, ldb, (t + 1) * 32,
                     sA + (cur ^ 1) * ASLOT, sB + (cur ^ 1) * BSLOT);
    const __bf16* cA = sA + cur * ASLOT;
    const __bf16* cB = sB + cur * BSLOT;
    bf16x8 af[MH], bfr[4];
#pragma unroll
    for (int mi = 0; mi < MH; ++mi) {
      const int r = wm + mi * 16 + fr;
      af[mi] = *(const bf16x8*)(cA + r * 32 + (fgh ^ ((r >> 1) & 3)) * 8);
    }
#pragma unroll
    for (int ni = 0; ni < 4; ++ni) {
      const int r = wn + ni * 16 + fr;
      bfr[ni] = *(const bf16x8*)(cB + r * 32 + (fgh ^ ((r >> 1) & 3)) * 8);
    }
    __builtin_amdgcn_s_setprio(1);
#pragma unroll
    for (int mi = 0; mi < MH; ++mi)
#pragma unroll
      for (int ni = 0; ni < 4; ++ni)
        acc[mi][ni] = __builtin_amdgcn_mfma_f32_16x16x32_bf16(af[mi], bfr[ni], acc[mi][ni], 0, 0, 0);
    __builtin_amdgcn_s_setprio(0);
    if (t + 1 < nt) {
      asm volatile("s_waitcnt vmcnt(0)" ::: "memory");
      __syncthreads();
      cur ^= 1;
    }
  }
}

// ===========================================================================
// K2: mid — one launch (grid 288): id<32 small GEMMs -> Aproj; id>=32 R.
// ===========================================================================
__global__ __launch_bounds__(256, 4) void mid_kernel(
    const __bf16* __restrict__ wqT, const __bf16* __restrict__ wkT,
    const __bf16* __restrict__ wvT, const __bf16* __restrict__ wob,
    const __bf16* __restrict__ xnT, const float* __restrict__ rvec,
    __bf16* __restrict__ Aproj, float* __restrict__ R) {
  __shared__ __align__(16) __bf16 sA[2 * 128 * 32], sB[2 * 128 * 32];
  const int id = blockIdx.x;
  if (id < 32) {
    const bool doM = id < 16;
    const int sub = doM ? id : id - 16;
    const int mt = sub >> 2, nt2 = sub & 3;
    const __bf16* A = doM ? (wqT + (size_t)mt * 128 * NC) : (wob + (size_t)mt * 128 * NC);
    const __bf16* B = doM ? (wkT + (size_t)nt2 * 128 * NC) : (wvT + (size_t)nt2 * 128 * NC);
    f32x4 acc[4][4] = {};
    gemm_core32<128>(A, NC, B, NC, NC, sA, sB, acc);

    const int tid = threadIdx.x;
    const int lane = tid & 63, wave = tid >> 6;
    const int wm = (wave >> 1) * 64, wn = (wave & 1) * 64;
    const int fr = lane & 15, fq4 = (lane >> 4) * 4;
    const int mbase = (doM ? 0 : NC) + mt * 128;
#pragma unroll
    for (int mi = 0; mi < 4; ++mi) {
      const int m = mbase + wm + mi * 16 + fq4;
#pragma unroll
      for (int ni = 0; ni < 4; ++ni) {
        const int n = nt2 * 128 + wn + ni * 16 + fr;
#pragma unroll
        for (int r = 0; r < 4; ++r)
          Aproj[(size_t)(m + r) * NC + n] = tob(acc[mi][ni][r]);
      }
    }
  } else {
    const int id2 = id - 32;
    const int L = (id2 & 7) * 32 + (id2 >> 3);  // CPX=32 -> XCD=b/2
    const int b = L >> 4, j0 = (L & 15) * 64;
    const int row = threadIdx.x >> 2, q = threadIdx.x & 3;
    const __bf16* src = xnT + ((size_t)(b * NSPA) + j0 + row) * NC + q * 128;
    const float* rv = rvec + q * 128;
    float s = 0.f;
#pragma unroll
    for (int i = 0; i < 16; ++i) {
      bf16x8 v = *(const bf16x8*)(src + i * 8);
#pragma unroll
      for (int e = 0; e < 8; ++e) s += (float)v[e] * rv[i * 8 + e];
    }
    s += __shfl_xor(s, 1);
    s += __shfl_xor(s, 2);
    if (q == 0) R[b * NSPA + j0 + row] = s;
  }
}

// ---------------------------------------------------------------------------
// K3: proj GEMM. C[m][n=(b,j)] = Aproj[m][:] . xn_j
//   m <  512: transposed store -> Yt[b][j][c]
//   m >= 512: natural store -> v'[b][d][j] + bc[d]
// grid 1024 (CPX=128 -> XCD=b/2); 4 blocks/CU -> whole grid co-resident.
// ---------------------------------------------------------------------------
__global__ __launch_bounds__(256, 4) void proj_kernel(
    const __bf16* __restrict__ Aproj, const __bf16* __restrict__ xnT,
    const float* __restrict__ bc, __bf16* __restrict__ Yt, __bf16* __restrict__ vp) {
  const int L = xcd_swz(128);
  const int pair = L >> 3, mblk = L & 7;
  const int b = pair >> 3;
  const int n0 = (pair & 7) * 128, m0 = mblk * 128;
  __shared__ __align__(16) __bf16 sA[2 * 128 * 32], sB[2 * 128 * 32];
  f32x4 acc[4][4] = {};
  gemm_core32<128>(Aproj + (size_t)m0 * NC, NC, xnT + ((size_t)b * NSPA + n0) * NC, NC,
                   NC, sA, sB, acc);

  const int lane = threadIdx.x & 63, wave = threadIdx.x >> 6;
  const int wm = (wave >> 1) * 64, wn = (wave & 1) * 64;
  const int fr = lane & 15, fq4 = (lane >> 4) * 4;
  if (m0 < NC) {  // Y path: transposed store
#pragma unroll
    for (int mi = 0; mi < 4; ++mi) {
      const int m = m0 + wm + mi * 16 + fq4;
#pragma unroll
      for (int ni = 0; ni < 4; ++ni) {
        const int n = n0 + wn + ni * 16 + fr;
        bf16x4 w;
        w[0] = tob(acc[mi][ni][0]);
        w[1] = tob(acc[mi][ni][1]);
        w[2] = tob(acc[mi][ni][2]);
        w[3] = tob(acc[mi][ni][3]);
        *(bf16x4*)(Yt + ((size_t)b * NSPA + n) * NC + m) = w;
      }
    }
  } else {  // v' path: natural store + bc
#pragma unroll
    for (int mi = 0; mi < 4; ++mi) {
      const int m = m0 + wm + mi * 16 + fq4;
      const int d = m - NC;
      const float4 bias = *(const float4*)(bc + d);
#pragma unroll
      for (int ni = 0; ni < 4; ++ni) {
        const int n = n0 + wn + ni * 16 + fr;
        vp[((size_t)b * NC + d + 0) * NSPA + n] = tob(acc[mi][ni][0] + bias.x);
        vp[((size_t)b * NC + d + 1) * NSPA + n] = tob(acc[mi][ni][1] + bias.y);
        vp[((size_t)b * NC + d + 2) * NSPA + n] = tob(acc[mi][ni][2] + bias.z);
        vp[((size_t)b * NC + d + 3) * NSPA + n] = tob(acc[mi][ni][3] + bias.w);
      }
    }
  }
}

// ---------------------------------------------------------------------------
// K4: scores (swapped). C[j][i] = Y_j . xn_i; P[b][i][j] = (dot + R[b][j])*SCL
// grid 1024 (CPX=128 -> XCD=b/2); 4 blocks/CU.
// ---------------------------------------------------------------------------
__global__ __launch_bounds__(256, 4) void scores_kernel(
    const __bf16* __restrict__ Yt, const __bf16* __restrict__ xnT,
    const float* __restrict__ R, __bf16* __restrict__ P) {
  const int L = xcd_swz(128);
  const int b = L >> 6, r = L & 63;
  const int i0 = (r >> 3) * 128, j0 = (r & 7) * 128;
  __shared__ __align__(16) __bf16 sA[2 * 128 * 32], sB[2 * 128 * 32];
  f32x4 acc[4][4] = {};
  gemm_core32<128>(Yt + ((size_t)b * NSPA + j0) * NC, NC,
                   xnT + ((size_t)b * NSPA + i0) * NC, NC, NC, sA, sB, acc);

  const int lane = threadIdx.x & 63, wave = threadIdx.x >> 6;
  const int wm = (wave >> 1) * 64, wn = (wave & 1) * 64;
  const int fr = lane & 15, fq4 = (lane >> 4) * 4;
#pragma unroll
  for (int mi = 0; mi < 4; ++mi) {
    const int j = j0 + wm + mi * 16 + fq4;
    const float4 Rb = *(const float4*)(R + b * NSPA + j);
#pragma unroll
    for (int ni = 0; ni < 4; ++ni) {
      const int i = i0 + wn + ni * 16 + fr;
      bf16x4 w;
      w[0] = tob((acc[mi][ni][0] + Rb.x) * SCL);
      w[1] = tob((acc[mi][ni][1] + Rb.y) * SCL);
      w[2] = tob((acc[mi][ni][2] + Rb.z) * SCL);
      w[3] = tob((acc[mi][ni][3] + Rb.w) * SCL);
      *(bf16x4*)(P + ((size_t)b * NSPA + i) * NSPA + j) = w;
    }
  }
}

// ---------------------------------------------------------------------------
// K5: in-place row softmax, wave-per-row, 16 rows/block. grid 1024 (CPX=128)
// ---------------------------------------------------------------------------
__global__ void softmax_kernel(__bf16* __restrict__ P) {
  const int L = xcd_swz(128);
  const int base_row = L * 16 + (threadIdx.x >> 6) * 4;
  const int lane = threadIdx.x & 63;
#pragma unroll
  for (int r = 0; r < 4; ++r) {
    __bf16* p = P + (size_t)(base_row + r) * NSPA + lane * 16;
    bf16x8 v0 = *(const bf16x8*)p;
    bf16x8 v1 = *(const bf16x8*)(p + 8);
    float f[16];
#pragma unroll
    for (int i = 0; i < 8; ++i) { f[i] = (float)v0[i]; f[8 + i] = (float)v1[i]; }
    float m = f[0];
#pragma unroll
    for (int i = 1; i < 16; ++i) m = fmaxf(m, f[i]);
#pragma unroll
    for (int off = 32; off; off >>= 1) m = fmaxf(m, __shfl_xor(m, off));
    float s = 0.f;
#pragma unroll
    for (int i = 0; i < 16; ++i) { f[i] = __expf(f[i] - m); s += f[i]; }
#pragma unroll
    for (int off = 32; off; off >>= 1) s += __shfl_xor(s, off);
    const float inv = 1.f / s;
#pragma unroll
    for (int i = 0; i < 8; ++i) { v0[i] = tob(f[i] * inv); v1[i] = tob(f[8 + i] * inv); }
    *(bf16x8*)p = v0;
    *(bf16x8*)(p + 8) = v1;
  }
}

// ---------------------------------------------------------------------------
// K6: PV + out fused, A-tile 64 rows (MROWS=64) so grid = 1024 -> 4 blocks/CU.
// C[d][i] = v'[d][:] . P[i][:] (K=1024); out = C + bout + x (fp32)
// grid 1024 (CPX=128 -> XCD=b/2): b=L>>6, r=L&63, d0=(r>>3)*64, i0=(r&7)*128
// ---------------------------------------------------------------------------
__global__ __launch_bounds__(256, 4) void pvout_kernel(
    const __bf16* __restrict__ vp, const __bf16* __restrict__ P,
    const float* __restrict__ bout, const float* __restrict__ x,
    float* __restrict__ out) {
  const int L = xcd_swz(128);
  const int b = L >> 6, r = L & 63;
  const int d0 = (r >> 3) * 64, i0 = (r & 7) * 128;
  __shared__ __align__(16) __bf16 sA[2 * 64 * 32], sB[2 * 128 * 32];
  f32x4 acc[2][4] = {};
  gemm_core32<64>(vp + ((size_t)b * NC + d0) * NSPA, NSPA,
                  P + ((size_t)b * NSPA + i0) * NSPA, NSPA, NSPA, sA, sB, acc);

  const int lane = threadIdx.x & 63, wave = threadIdx.x >> 6;
  const int wm = (wave >> 1) * 32, wn = (wave & 1) * 64;
  const int fr = lane & 15, fq4 = (lane >> 4) * 4;
#pragma unroll
  for (int mi = 0; mi < 2; ++mi) {
    const int d = d0 + wm + mi * 16 + fq4;
    const float4 bias = *(const float4*)(bout + d);
#pragma unroll
    for (int ni = 0; ni < 4; ++ni) {
      const int i = i0 + wn + ni * 16 + fr;
      const size_t ix = ((size_t)b * NC + d) * NSPA + i;
      out[ix + 0 * NSPA] = acc[mi][ni][0] + bias.x + x[ix + 0 * NSPA];
      out[ix + 1 * NSPA] = acc[mi][ni][1] + bias.y + x[ix + 1 * NSPA];
      out[ix + 2 * NSPA] = acc[mi][ni][2] + bias.z + x[ix + 2 * NSPA];
      out[ix + 3 * NSPA] = acc[mi][ni][3] + bias.w + x[ix + 3 * NSPA];
    }
  }
}

// ---------------------------------------------------------------------------
// Workspace (~67 MB):
//   rvec/bc 4KB | R 64KB | wqT/wkT/wvT/wob 2MB | Aproj 1MB
//   xnT 16MB | v' 16MB | P 32MB.   Yt (16MB) lives in d_out (dead til pvout).
// ---------------------------------------------------------------------------
extern "C" void kernel_launch(void* const* d_in, const int* in_sizes, int n_in,
                              void* d_out, int out_size, void* d_ws, size_t ws_size,
                              hipStream_t stream) {
  const float* x        = (const float*)d_in[0];
  const float* gn_scale = (const float*)d_in[3];
  const float* gn_bias  = (const float*)d_in[4];
  const float* w_qkv    = (const float*)d_in[5];
  const float* b_qkv    = (const float*)d_in[6];
  const float* w_out    = (const float*)d_in[7];
  const float* b_out    = (const float*)d_in[8];
  float* out = (float*)d_out;

  float*  rvec  = (float*)d_ws;                 // 512
  float*  bc    = rvec + NC;                    // 512
  float*  R     = bc + NC;                      // 16384
  __bf16* wqT   = (__bf16*)(R + NB * NSPA);     // 256K elems
  __bf16* wkT   = wqT + NC * NC;
  __bf16* wvT   = wkT + NC * NC;
  __bf16* wob   = wvT + NC * NC;
  __bf16* Aproj = wob + NC * NC;                // 1024x512
  __bf16* xnT   = Aproj + 2 * NC * NC;          // 8M elems
  __bf16* vp    = xnT + (size_t)NB * NSPA * NC; // 8M elems
  __bf16* P     = vp + (size_t)NB * NC * NSPA;  // 16M elems
  __bf16* Yt    = (__bf16*)d_out;               // 16MB scratch in d_out

  prep_kernel<<<dim3(784), 256, 0, stream>>>(x, gn_scale, gn_bias, w_qkv, w_out,
                                             b_qkv, xnT, wqT, wkT, wvT, wob, rvec, bc);
  mid_kernel<<<dim3(288), 256, 0, stream>>>(wqT, wkT, wvT, wob, xnT, rvec, Aproj, R);
  proj_kernel<<<dim3(1024), 256, 0, stream>>>(Aproj, xnT, bc, Yt, vp);
  scores_kernel<<<dim3(1024), 256, 0, stream>>>(Yt, xnT, R, P);
  softmax_kernel<<<dim3(1024), 256, 0, stream>>>(P);
  pvout_kernel<<<dim3(1024), 256, 0, stream>>>(vp, P, b_out, x, out);
}

// Round 11
// 130.437 us; speedup vs baseline: 1.1168x; 1.1168x over previous
//
#include <hip/hip_runtime.h>
#include <hip/hip_bf16.h>

// Shapes (fixed by the problem)
#define NB   16    // batch
#define NC   512   // channels
#define NSPA 1024  // h*w
#define GN_EPS 1e-5f
#define SCL 0.044194173824159216f  // 512^-0.5

typedef __bf16 bf16x8 __attribute__((ext_vector_type(8)));
typedef __bf16 bf16x4 __attribute__((ext_vector_type(4)));
typedef float  f32x4  __attribute__((ext_vector_type(4)));

typedef __attribute__((address_space(3))) void lds_t;
typedef const __attribute__((address_space(1))) void gl_t;
#define GLDS16(g, l) __builtin_amdgcn_global_load_lds((gl_t*)(g), (lds_t*)(l), 16, 0, 0)

__device__ __forceinline__ __bf16 tob(float f) { return (__bf16)f; }

// Bijective XCD-chunk swizzle (T1): each XCD gets a contiguous logical chunk.
__device__ __forceinline__ int xcd_swz(int cpx) {
  return (blockIdx.x & 7) * cpx + (blockIdx.x >> 3);
}

// ===========================================================================
// K1: prep — one launch, heterogeneous blocks (grid 788):
//   id <  512 : fused GroupNorm(stats+apply) + transpose -> xnT[b][n][c] bf16
//   id <  704 : 64x64 transpose tiles wqT/wkT/wvT[c][o] bf16  (192 blocks)
//   id <  768 : pack Wout natural -> wob bf16                  (64 blocks)
//   id <  776 : rvec[c] = sum_o Wk[o][c]*bq[o]                 (8 blocks)
//   id <  784 : bc[o]   = sum_c Wout[o][c]*bv[c]               (8 blocks)
//   id <  788 : zero rowsum[16384] (must re-zero every call)   (4 blocks)
// ===========================================================================
__global__ void prep_kernel(const float* __restrict__ x,
                            const float* __restrict__ gn_scale,
                            const float* __restrict__ gn_bias,
                            const float* __restrict__ wq,   // w_qkv [1536][512]
                            const float* __restrict__ wo,   // w_out [512][512]
                            const float* __restrict__ bqkv, // [1536]
                            __bf16* __restrict__ xnT, __bf16* __restrict__ wqT,
                            __bf16* __restrict__ wkT, __bf16* __restrict__ wvT,
                            __bf16* __restrict__ wob, float* __restrict__ rvec,
                            float* __restrict__ bc, float* __restrict__ rowsum) {
  __shared__ __align__(16) unsigned char smem[37120];
  const int id = blockIdx.x;
  const int t = threadIdx.x;
  if (id < 512) {
    const int L = (id & 7) * 64 + (id >> 3);   // XCD-chunk swizzle (CPX=64)
    const int b = L >> 5, g = L & 31;
    const int row = t >> 4, sub = t & 15;
    const float4* bx = (const float4*)(x + (size_t)(b * NC + g * 16 + row) * NSPA);
    float4 vv[16];
    float s = 0.f, ss = 0.f;
#pragma unroll
    for (int k = 0; k < 16; ++k) {
      float4 v = bx[sub + k * 16];
      vv[k] = v;
      s  += (v.x + v.y) + (v.z + v.w);
      ss += (v.x * v.x + v.y * v.y) + (v.z * v.z + v.w * v.w);
    }
#pragma unroll
    for (int off = 32; off; off >>= 1) { s += __shfl_xor(s, off); ss += __shfl_xor(ss, off); }
    float* red = (float*)(smem + 36864);
    const int wave = t >> 6, lane = t & 63;
    if (lane == 0) { red[wave] = s; red[4 + wave] = ss; }
    __syncthreads();
    const float S  = red[0] + red[1] + red[2] + red[3];
    const float SS = red[4] + red[5] + red[6] + red[7];
    const float mean = S * (1.f / 16384.f);
    const float var  = SS * (1.f / 16384.f) - mean * mean;
    const float rstd = rsqrtf(var + GN_EPS);
    const int c = g * 16 + row;
    const float a  = gn_scale[c] * rstd;
    const float bb = gn_bias[c] - mean * a;
    __bf16 (*lt)[18] = (__bf16(*)[18])smem;   // [1024][16+2pad] bf16
#pragma unroll
    for (int k = 0; k < 16; ++k) {
      float4 v = vv[k];
      const int n0 = (sub + k * 16) * 4;
      lt[n0 + 0][row] = tob(v.x * a + bb);
      lt[n0 + 1][row] = tob(v.y * a + bb);
      lt[n0 + 2][row] = tob(v.z * a + bb);
      lt[n0 + 3][row] = tob(v.w * a + bb);
    }
    __syncthreads();
#pragma unroll
    for (int r = 0; r < 4; ++r) {
      const int n = t * 4 + r;
      const unsigned int* lr = (const unsigned int*)&lt[n][0];
      uint4 d0, d1;
      d0.x = lr[0]; d0.y = lr[1]; d0.z = lr[2]; d0.w = lr[3];
      d1.x = lr[4]; d1.y = lr[5]; d1.z = lr[6]; d1.w = lr[7];
      uint4* dst = (uint4*)(xnT + (size_t)(b * NSPA + n) * NC + g * 16);
      dst[0] = d0; dst[1] = d1;
    }
  } else if (id < 704) {
    const int id2 = id - 512;
    const int mat = id2 >> 6, tile = id2 & 63;
    const int o0 = (tile >> 3) * 64, c0 = (tile & 7) * 64;
    __bf16* dstT = (mat == 0) ? wqT : (mat == 1) ? wkT : wvT;
    __bf16 (*l)[72] = (__bf16(*)[72])smem;
    const int orr = t >> 2, seg = (t & 3) * 16;
    const float4* src = (const float4*)(wq + (size_t)(mat * NC + o0 + orr) * NC + c0 + seg);
#pragma unroll
    for (int i = 0; i < 4; ++i) {
      float4 v = src[i];
      l[seg + i * 4 + 0][orr] = tob(v.x);
      l[seg + i * 4 + 1][orr] = tob(v.y);
      l[seg + i * 4 + 2][orr] = tob(v.z);
      l[seg + i * 4 + 3][orr] = tob(v.w);
    }
    __syncthreads();
#pragma unroll
    for (int i = 0; i < 2; ++i) {
      const int chunk = t + i * 256;
      const int row = chunk >> 3, sg = chunk & 7;
      *(bf16x8*)(dstT + (size_t)(c0 + row) * NC + o0 + sg * 8) = *(const bf16x8*)&l[row][sg * 8];
    }
  } else if (id < 768) {
    const int idx = id - 704;
#pragma unroll
    for (int i = 0; i < 4; ++i) {
      const int tt = idx * 1024 + i * 256 + t;
      float4 v = ((const float4*)wo)[tt];
      bf16x4 w;
      w[0] = tob(v.x); w[1] = tob(v.y); w[2] = tob(v.z); w[3] = tob(v.w);
      *(bf16x4*)(wob + (size_t)tt * 4) = w;
    }
  } else if (id < 776) {
    const int c0 = (id - 768) * 64;
    const int lane = t & 63, wave = t >> 6;
    const int c = c0 + lane;
    float s = 0.f;
    for (int o = wave * 128; o < wave * 128 + 128; ++o)
      s += wq[(size_t)(NC + o) * NC + c] * bqkv[o];
    float* red = (float*)smem;
    red[wave * 64 + lane] = s;
    __syncthreads();
    if (wave == 0) {
      float tot = red[lane] + red[64 + lane] + red[128 + lane] + red[192 + lane];
      rvec[c] = tot;
    }
  } else if (id < 784) {
    const int o = (id - 776) * 64 + (t >> 2);
    const int q = t & 3;
    const float4* wr = (const float4*)(wo + (size_t)o * NC + q * 128);
    const float4* bv = (const float4*)(bqkv + 2 * NC + q * 128);
    float s = 0.f;
#pragma unroll
    for (int i = 0; i < 32; ++i) {
      float4 w4 = wr[i], b4 = bv[i];
      s += (w4.x * b4.x + w4.y * b4.y) + (w4.z * b4.z + w4.w * b4.w);
    }
    s += __shfl_xor(s, 1);
    s += __shfl_xor(s, 2);
    if (q == 0) bc[o] = s;
  } else {
    // zero rowsum: 4 blocks x 4096 floats
    float4* dst = (float4*)(rowsum + (id - 784) * 4096);
#pragma unroll
    for (int i = 0; i < 4; ++i) dst[i * 256 + t] = make_float4(0.f, 0.f, 0.f, 0.f);
  }
}

// ---------------------------------------------------------------------------
// r3 2-phase 128^2 BK=64 core (proven): XOR-swizzled LDS (0 conflicts),
// dbuf, setprio.
// ---------------------------------------------------------------------------
__device__ __forceinline__ void stage_pair(const __bf16* __restrict__ A, int lda,
                                           const __bf16* __restrict__ B, int ldb,
                                           int k0, __bf16* lAf, __bf16* lBf) {
  const int tid = threadIdx.x;
#pragma unroll
  for (int i = 0; i < 4; ++i) {
    const int idx = tid + i * 256;
    const int srow = idx >> 3;
    const int ss = ((idx & 7) ^ (srow & 7)) * 8;
    GLDS16(A + (size_t)srow * lda + k0 + ss, lAf + idx * 8);
    GLDS16(B + (size_t)srow * ldb + k0 + ss, lBf + idx * 8);
  }
}

__device__ __forceinline__ void gemm_core_db(const __bf16* __restrict__ A, int lda,
                                             const __bf16* __restrict__ B, int ldb,
                                             int K, __bf16 (*lA)[128][64],
                                             __bf16 (*lB)[128][64], f32x4 acc[4][4]) {
  const int tid = threadIdx.x;
  const int lane = tid & 63, wave = tid >> 6;
  const int wm = (wave >> 1) * 64, wn = (wave & 1) * 64;
  const int fr = lane & 15, fg = (lane >> 4) * 8;
  const int nt = K >> 6;

  stage_pair(A, lda, B, ldb, 0, &lA[0][0][0], &lB[0][0][0]);
  asm volatile("s_waitcnt vmcnt(0)" ::: "memory");
  __syncthreads();
  int cur = 0;
  for (int t = 0; t < nt; ++t) {
    if (t + 1 < nt)
      stage_pair(A, lda, B, ldb, (t + 1) * 64, &lA[cur ^ 1][0][0], &lB[cur ^ 1][0][0]);
    __builtin_amdgcn_s_setprio(1);
#pragma unroll
    for (int ks = 0; ks < 2; ++ks) {
      bf16x8 af[4], bfr[4];
#pragma unroll
      for (int mi = 0; mi < 4; ++mi) {
        const int r = wm + mi * 16 + fr;
        af[mi] = *(const bf16x8*)&lA[cur][r][(ks * 32 + fg) ^ ((r & 7) << 3)];
      }
#pragma unroll
      for (int ni = 0; ni < 4; ++ni) {
        const int r = wn + ni * 16 + fr;
        bfr[ni] = *(const bf16x8*)&lB[cur][r][(ks * 32 + fg) ^ ((r & 7) << 3)];
      }
#pragma unroll
      for (int mi = 0; mi < 4; ++mi)
#pragma unroll
        for (int ni = 0; ni < 4; ++ni)
          acc[mi][ni] = __builtin_amdgcn_mfma_f32_16x16x32_bf16(af[mi], bfr[ni], acc[mi][ni], 0, 0, 0);
    }
    __builtin_amdgcn_s_setprio(0);
    if (t + 1 < nt) {
      asm volatile("s_waitcnt vmcnt(0)" ::: "memory");
      __syncthreads();
      cur ^= 1;
    }
  }
}

// ===========================================================================
// K2: mid — one launch (grid 288): id<32 small GEMMs -> Aproj; id>=32 R.
// ===========================================================================
__global__ __launch_bounds__(256, 2) void mid_kernel(
    const __bf16* __restrict__ wqT, const __bf16* __restrict__ wkT,
    const __bf16* __restrict__ wvT, const __bf16* __restrict__ wob,
    const __bf16* __restrict__ xnT, const float* __restrict__ rvec,
    __bf16* __restrict__ Aproj, float* __restrict__ R) {
  __shared__ __bf16 lA[2][128][64], lB[2][128][64];
  const int id = blockIdx.x;
  if (id < 32) {
    const bool doM = id < 16;
    const int sub = doM ? id : id - 16;
    const int mt = sub >> 2, nt2 = sub & 3;
    const __bf16* A = doM ? (wqT + (size_t)mt * 128 * NC) : (wob + (size_t)mt * 128 * NC);
    const __bf16* B = doM ? (wkT + (size_t)nt2 * 128 * NC) : (wvT + (size_t)nt2 * 128 * NC);
    f32x4 acc[4][4] = {};
    gemm_core_db(A, NC, B, NC, NC, lA, lB, acc);

    const int tid = threadIdx.x;
    const int lane = tid & 63, wave = tid >> 6;
    const int wm = (wave >> 1) * 64, wn = (wave & 1) * 64;
    const int fr = lane & 15, fq4 = (lane >> 4) * 4;
    const int mbase = (doM ? 0 : NC) + mt * 128;
#pragma unroll
    for (int mi = 0; mi < 4; ++mi) {
      const int m = mbase + wm + mi * 16 + fq4;
#pragma unroll
      for (int ni = 0; ni < 4; ++ni) {
        const int n = nt2 * 128 + wn + ni * 16 + fr;
#pragma unroll
        for (int r = 0; r < 4; ++r)
          Aproj[(size_t)(m + r) * NC + n] = tob(acc[mi][ni][r]);
      }
    }
  } else {
    const int id2 = id - 32;
    const int L = (id2 & 7) * 32 + (id2 >> 3);  // CPX=32 -> XCD=b/2
    const int b = L >> 4, j0 = (L & 15) * 64;
    const int row = threadIdx.x >> 2, q = threadIdx.x & 3;
    const __bf16* src = xnT + ((size_t)(b * NSPA) + j0 + row) * NC + q * 128;
    const float* rv = rvec + q * 128;
    float s = 0.f;
#pragma unroll
    for (int i = 0; i < 16; ++i) {
      bf16x8 v = *(const bf16x8*)(src + i * 8);
#pragma unroll
      for (int e = 0; e < 8; ++e) s += (float)v[e] * rv[i * 8 + e];
    }
    s += __shfl_xor(s, 1);
    s += __shfl_xor(s, 2);
    if (q == 0) R[b * NSPA + j0 + row] = s;
  }
}

// ---------------------------------------------------------------------------
// K3: proj GEMM. C[m][n=(b,j)] = Aproj[m][:] . xn_j
//   m <  512: transposed store -> Yt[b][j][c]
//   m >= 512: natural store -> v'[b][d][j] + bc[d]
// grid 1024 (CPX=128 -> XCD=b/2)
// ---------------------------------------------------------------------------
__global__ __launch_bounds__(256, 2) void proj_kernel(
    const __bf16* __restrict__ Aproj, const __bf16* __restrict__ xnT,
    const float* __restrict__ bc, __bf16* __restrict__ Yt, __bf16* __restrict__ vp) {
  const int L = xcd_swz(128);
  const int pair = L >> 3, mblk = L & 7;
  const int b = pair >> 3;
  const int n0 = (pair & 7) * 128, m0 = mblk * 128;
  __shared__ __bf16 lA[2][128][64], lB[2][128][64];
  f32x4 acc[4][4] = {};
  gemm_core_db(Aproj + (size_t)m0 * NC, NC, xnT + ((size_t)b * NSPA + n0) * NC, NC,
               NC, lA, lB, acc);

  const int lane = threadIdx.x & 63, wave = threadIdx.x >> 6;
  const int wm = (wave >> 1) * 64, wn = (wave & 1) * 64;
  const int fr = lane & 15, fq4 = (lane >> 4) * 4;
  if (m0 < NC) {  // Y path: transposed store
#pragma unroll
    for (int mi = 0; mi < 4; ++mi) {
      const int m = m0 + wm + mi * 16 + fq4;
#pragma unroll
      for (int ni = 0; ni < 4; ++ni) {
        const int n = n0 + wn + ni * 16 + fr;
        bf16x4 w;
        w[0] = tob(acc[mi][ni][0]);
        w[1] = tob(acc[mi][ni][1]);
        w[2] = tob(acc[mi][ni][2]);
        w[3] = tob(acc[mi][ni][3]);
        *(bf16x4*)(Yt + ((size_t)b * NSPA + n) * NC + m) = w;
      }
    }
  } else {  // v' path: natural store + bc
#pragma unroll
    for (int mi = 0; mi < 4; ++mi) {
      const int m = m0 + wm + mi * 16 + fq4;
      const int d = m - NC;
      const float4 bias = *(const float4*)(bc + d);
#pragma unroll
      for (int ni = 0; ni < 4; ++ni) {
        const int n = n0 + wn + ni * 16 + fr;
        vp[((size_t)b * NC + d + 0) * NSPA + n] = tob(acc[mi][ni][0] + bias.x);
        vp[((size_t)b * NC + d + 1) * NSPA + n] = tob(acc[mi][ni][1] + bias.y);
        vp[((size_t)b * NC + d + 2) * NSPA + n] = tob(acc[mi][ni][2] + bias.z);
        vp[((size_t)b * NC + d + 3) * NSPA + n] = tob(acc[mi][ni][3] + bias.w);
      }
    }
  }
}

// ---------------------------------------------------------------------------
// K4: scores + exp + rowsum (softmax pass deleted).
// C[j][i] = Y_j . xn_i; e = exp((dot + R[b][j]) * SCL) [no max-subtraction:
// fp32 headroom is ample for GN-scale scores]; P[b][i][j] = bf16(e);
// rowsum[b][i] += sum_j e  (shuffle-reduce over fq4 lane groups, then one
// atomicAdd per (wave, ni, fr); sums the ROUNDED bf16 values so the
// normalizer matches what PV consumes).
// grid 1024 (CPX=128 -> XCD=b/2)
// ---------------------------------------------------------------------------
__global__ __launch_bounds__(256, 2) void scores_kernel(
    const __bf16* __restrict__ Yt, const __bf16* __restrict__ xnT,
    const float* __restrict__ R, __bf16* __restrict__ P,
    float* __restrict__ rowsum) {
  const int L = xcd_swz(128);
  const int b = L >> 6, r = L & 63;
  const int i0 = (r >> 3) * 128, j0 = (r & 7) * 128;
  __shared__ __bf16 lA[2][128][64], lB[2][128][64];
  f32x4 acc[4][4] = {};
  gemm_core_db(Yt + ((size_t)b * NSPA + j0) * NC, NC,
               xnT + ((size_t)b * NSPA + i0) * NC, NC, NC, lA, lB, acc);

  const int lane = threadIdx.x & 63, wave = threadIdx.x >> 6;
  const int wm = (wave >> 1) * 64, wn = (wave & 1) * 64;
  const int fr = lane & 15, fq4 = (lane >> 4) * 4;
  float rsum[4] = {0.f, 0.f, 0.f, 0.f};
#pragma unroll
  for (int mi = 0; mi < 4; ++mi) {
    const int j = j0 + wm + mi * 16 + fq4;
    const float4 Rb = *(const float4*)(R + b * NSPA + j);
#pragma unroll
    for (int ni = 0; ni < 4; ++ni) {
      const int i = i0 + wn + ni * 16 + fr;
      bf16x4 w;
      w[0] = tob(__expf((acc[mi][ni][0] + Rb.x) * SCL));
      w[1] = tob(__expf((acc[mi][ni][1] + Rb.y) * SCL));
      w[2] = tob(__expf((acc[mi][ni][2] + Rb.z) * SCL));
      w[3] = tob(__expf((acc[mi][ni][3] + Rb.w) * SCL));
      rsum[ni] += ((float)w[0] + (float)w[1]) + ((float)w[2] + (float)w[3]);
      *(bf16x4*)(P + ((size_t)b * NSPA + i) * NSPA + j) = w;
    }
  }
  // reduce over the 4 fq4 groups (lane bits 4,5), then atomicAdd per row
#pragma unroll
  for (int ni = 0; ni < 4; ++ni) {
    rsum[ni] += __shfl_xor(rsum[ni], 16);
    rsum[ni] += __shfl_xor(rsum[ni], 32);
  }
  if (lane < 16) {
#pragma unroll
    for (int ni = 0; ni < 4; ++ni)
      atomicAdd(&rowsum[b * NSPA + i0 + wn + ni * 16 + fr], rsum[ni]);
  }
}

// ---------------------------------------------------------------------------
// K5: PV + normalize + out fused. C[d][i] = v'[d][:] . P[i][:] (K=1024);
// out[b][d][i] = C / rowsum[b][i] + bout[d] + x[b][d][i]  (fp32)
// grid 512 (CPX=64 -> XCD=b/2)
// ---------------------------------------------------------------------------
__global__ __launch_bounds__(256, 2) void pvout_kernel(
    const __bf16* __restrict__ vp, const __bf16* __restrict__ P,
    const float* __restrict__ rowsum, const float* __restrict__ bout,
    const float* __restrict__ x, float* __restrict__ out) {
  const int L = xcd_swz(64);
  const int b = L >> 5, r = L & 31;
  const int d0 = (r >> 3) * 128, i0 = (r & 7) * 128;
  __shared__ __bf16 lA[2][128][64], lB[2][128][64];
  f32x4 acc[4][4] = {};
  gemm_core_db(vp + ((size_t)b * NC + d0) * NSPA, NSPA,
               P + ((size_t)b * NSPA + i0) * NSPA, NSPA, NSPA, lA, lB, acc);

  const int lane = threadIdx.x & 63, wave = threadIdx.x >> 6;
  const int wm = (wave >> 1) * 64, wn = (wave & 1) * 64;
  const int fr = lane & 15, fq4 = (lane >> 4) * 4;
  float inv[4];
#pragma unroll
  for (int ni = 0; ni < 4; ++ni)
    inv[ni] = 1.f / rowsum[b * NSPA + i0 + wn + ni * 16 + fr];
#pragma unroll
  for (int mi = 0; mi < 4; ++mi) {
    const int d = d0 + wm + mi * 16 + fq4;
    const float4 bias = *(const float4*)(bout + d);
#pragma unroll
    for (int ni = 0; ni < 4; ++ni) {
      const int i = i0 + wn + ni * 16 + fr;
      const size_t ix = ((size_t)b * NC + d) * NSPA + i;
      out[ix + 0 * NSPA] = acc[mi][ni][0] * inv[ni] + bias.x + x[ix + 0 * NSPA];
      out[ix + 1 * NSPA] = acc[mi][ni][1] * inv[ni] + bias.y + x[ix + 1 * NSPA];
      out[ix + 2 * NSPA] = acc[mi][ni][2] * inv[ni] + bias.z + x[ix + 2 * NSPA];
      out[ix + 3 * NSPA] = acc[mi][ni][3] * inv[ni] + bias.w + x[ix + 3 * NSPA];
    }
  }
}

// ---------------------------------------------------------------------------
// Workspace (~67 MB):
//   rvec/bc 4KB | R 64KB | rowsum 64KB | wqT/wkT/wvT/wob 2MB | Aproj 1MB
//   xnT 16MB | v' 16MB | P 32MB.   Yt (16MB) lives in d_out (dead til pvout).
// ---------------------------------------------------------------------------
extern "C" void kernel_launch(void* const* d_in, const int* in_sizes, int n_in,
                              void* d_out, int out_size, void* d_ws, size_t ws_size,
                              hipStream_t stream) {
  const float* x        = (const float*)d_in[0];
  const float* gn_scale = (const float*)d_in[3];
  const float* gn_bias  = (const float*)d_in[4];
  const float* w_qkv    = (const float*)d_in[5];
  const float* b_qkv    = (const float*)d_in[6];
  const float* w_out    = (const float*)d_in[7];
  const float* b_out    = (const float*)d_in[8];
  float* out = (float*)d_out;

  float*  rvec   = (float*)d_ws;                 // 512
  float*  bc     = rvec + NC;                    // 512
  float*  R      = bc + NC;                      // 16384
  float*  rowsum = R + NB * NSPA;                // 16384
  __bf16* wqT    = (__bf16*)(rowsum + NB * NSPA);
  __bf16* wkT    = wqT + NC * NC;
  __bf16* wvT    = wkT + NC * NC;
  __bf16* wob    = wvT + NC * NC;
  __bf16* Aproj  = wob + NC * NC;                // 1024x512
  __bf16* xnT    = Aproj + 2 * NC * NC;          // 8M elems
  __bf16* vp     = xnT + (size_t)NB * NSPA * NC; // 8M elems
  __bf16* P      = vp + (size_t)NB * NC * NSPA;  // 16M elems
  __bf16* Yt     = (__bf16*)d_out;               // 16MB scratch in d_out

  prep_kernel<<<dim3(788), 256, 0, stream>>>(x, gn_scale, gn_bias, w_qkv, w_out,
                                             b_qkv, xnT, wqT, wkT, wvT, wob, rvec,
                                             bc, rowsum);
  mid_kernel<<<dim3(288), 256, 0, stream>>>(wqT, wkT, wvT, wob, xnT, rvec, Aproj, R);
  proj_kernel<<<dim3(1024), 256, 0, stream>>>(Aproj, xnT, bc, Yt, vp);
  scores_kernel<<<dim3(1024), 256, 0, stream>>>(Yt, xnT, R, P, rowsum);
  pvout_kernel<<<dim3(512), 256, 0, stream>>>(vp, P, rowsum, b_out, x, out);
}